// Round 1
// baseline (1853.261 us; speedup 1.0000x reference)
//
#include <hip/hip_runtime.h>
#include <math.h>

#define NEGV -1e20f

typedef __attribute__((ext_vector_type(4))) float floatx4;
typedef __attribute__((ext_vector_type(8))) short short8;
typedef __attribute__((ext_vector_type(4))) short short4v;

// B=8, T=512, S=128, C=512, S1=129, T1=513, R=19 (hard-coded for this problem)

__device__ __forceinline__ float lae(float a, float b){
  float mx = fmaxf(a, b);
  float mn = fminf(a, b);
  return mx + log1pf(__expf(mn - mx));   // exp underflows to 0 for big gaps -> exact
}

__device__ __forceinline__ short f2bf(float x){  // f32 -> bf16 RNE
  union { float f; unsigned u; } v; v.f = x;
  unsigned r = v.u + 0x7fffu + ((v.u >> 16) & 1u);
  return (short)(r >> 16);
}

__device__ __forceinline__ float fast_tanh(float x){
  x = fminf(fmaxf(x, -15.f), 15.f);
  float e = __expf(2.f * x);
  return (e - 1.f) / (e + 1.f);
}

// ---------- per-row max (+ optional logsumexp) over C=512 ----------
__global__ __launch_bounds__(256) void k_row_stats(
    const float* __restrict__ in, float* __restrict__ outMax, float* __restrict__ outLse)
{
  int row = blockIdx.x;
  const float* r = in + (size_t)row * 512;
  int tid = threadIdx.x;
  float v0 = r[tid], v1 = r[tid + 256];
  float m = fmaxf(v0, v1);
  #pragma unroll
  for (int off = 32; off; off >>= 1) m = fmaxf(m, __shfl_xor(m, off, 64));
  __shared__ float sm[4];
  __shared__ float sbm;
  int wv = tid >> 6;
  if ((tid & 63) == 0) sm[wv] = m;
  __syncthreads();
  if (tid == 0) sbm = fmaxf(fmaxf(sm[0], sm[1]), fmaxf(sm[2], sm[3]));
  __syncthreads();
  float mx = sbm;
  if (tid == 0) outMax[row] = mx;
  if (outLse){
    float s = __expf(v0 - mx) + __expf(v1 - mx);
    #pragma unroll
    for (int off = 32; off; off >>= 1) s += __shfl_xor(s, off, 64);
    __shared__ float sp[4];
    if ((tid & 63) == 0) sp[wv] = s;
    __syncthreads();
    if (tid == 0) outLse[row] = mx + __logf(sp[0] + sp[1] + sp[2] + sp[3]);
  }
}

// ---------- transpose + bf16-convert joiner_w: Wb[d][c] = bf16(W[c][d]) ----------
__global__ __launch_bounds__(256) void k_wb(const float* __restrict__ W, short* __restrict__ Wb){
  int idx = blockIdx.x * 256 + threadIdx.x;   // 262144 total
  int d = idx >> 9, c = idx & 511;
  Wb[idx] = f2bf(W[c * 512 + d]);
}

// ---------- normalizers: norm[b,s,t] = log(dot(exp(lm-lmmax), exp(am-ammax))) + maxes ----------
__global__ __launch_bounds__(256) void k_norm(
    const float* __restrict__ am, const float* __restrict__ lm,
    const float* __restrict__ lmMax, const float* __restrict__ amMax,
    float* __restrict__ normv)
{
  int b = blockIdx.z;
  int s0 = blockIdx.y * 16;
  int t0 = blockIdx.x * 128;
  __shared__ float lmS[16][68];
  __shared__ float amS[128][68];
  int tid = threadIdx.x;
  int ts = tid >> 4, tt = tid & 15;
  float acc[8];
  #pragma unroll
  for (int j = 0; j < 8; ++j) acc[j] = 0.f;

  for (int k0 = 0; k0 < 512; k0 += 64){
    { // stage lm tile 16x64 (exp fused)
      int e = tid * 4;
      int rr = e >> 6, cc = e & 63;
      int s = s0 + rr;
      floatx4 o = {0.f, 0.f, 0.f, 0.f};
      if (s < 129){
        float mx = lmMax[b * 129 + s];
        floatx4 v = *(const floatx4*)(lm + ((size_t)(b * 129 + s)) * 512 + k0 + cc);
        o[0] = __expf(v[0] - mx); o[1] = __expf(v[1] - mx);
        o[2] = __expf(v[2] - mx); o[3] = __expf(v[3] - mx);
      }
      *(floatx4*)&lmS[rr][cc] = o;
    }
    #pragma unroll
    for (int i = 0; i < 8; ++i){ // stage am tile 128x64 (exp fused)
      int e = (tid + i * 256) * 4;
      int rr = e >> 6, cc = e & 63;
      float mx = amMax[b * 512 + t0 + rr];
      floatx4 v = *(const floatx4*)(am + ((size_t)(b * 512 + t0 + rr)) * 512 + k0 + cc);
      floatx4 o;
      o[0] = __expf(v[0] - mx); o[1] = __expf(v[1] - mx);
      o[2] = __expf(v[2] - mx); o[3] = __expf(v[3] - mx);
      *(floatx4*)&amS[rr][cc] = o;
    }
    __syncthreads();
    #pragma unroll 4
    for (int k = 0; k < 64; ++k){
      float a = lmS[ts][k];
      #pragma unroll
      for (int j = 0; j < 8; ++j) acc[j] += a * amS[tt + 16 * j][k];
    }
    __syncthreads();
  }
  int s = s0 + ts;
  if (s < 129){
    float lmx = lmMax[b * 129 + s];
    #pragma unroll
    for (int j = 0; j < 8; ++j){
      int t = t0 + tt + 16 * j;
      normv[((size_t)(b * 129 + s)) * 512 + t] = __logf(acc[j]) + lmx + amMax[b * 512 + t];
    }
  }
}

// ---------- smoothed px (B,S,T+1) and py (B,S+1,T) ----------
__global__ __launch_bounds__(256) void k_pxpy(
    const float* __restrict__ am, const float* __restrict__ lm,
    const int* __restrict__ targets, const float* __restrict__ normv,
    const float* __restrict__ lmLse, float* __restrict__ px, float* __restrict__ py)
{
  int bs = blockIdx.x;           // b*129 + s
  int b = bs / 129, s = bs % 129;
  float lm0 = lm[(size_t)bs * 512];
  float lse = lmLse[bs];
  int sym = 0; float lms = 0.f;
  if (s < 128){ sym = targets[b * 128 + s]; lms = lm[(size_t)bs * 512 + sym]; }
  const float* nrm = normv + (size_t)bs * 512;
  float* pyr = py + (size_t)bs * 512;
  float* pxr = px + (size_t)(b * 128 + s) * 513;   // only used when s<128
  for (int t = threadIdx.x; t < 513; t += 256){
    if (t < 512){
      float n = nrm[t];
      float a0 = am[((size_t)(b * 512 + t)) * 512];
      pyr[t] = 0.75f * (a0 + lm0 - n) + 0.25f * (lm0 - lse);
      if (s < 128){
        float as = am[((size_t)(b * 512 + t)) * 512 + sym];
        pxr[t] = 0.75f * (as + lms - n) + 0.25f * (lms - lse);
      }
    } else if (s < 128){
      pxr[t] = NEGV;
    }
  }
}

// ---------- forward lattice DP (wavefront), writes p and tot=p[S,T] ----------
__global__ __launch_bounds__(192) void k_dp_fwd(
    const float* __restrict__ px, const float* __restrict__ py,
    float* __restrict__ p, float* __restrict__ tot)
{
  int b = blockIdx.x;
  int s = threadIdx.x;
  __shared__ float dbuf[2][132];
  const float* pxb = px + (size_t)b * (128 * 513);
  const float* pyb = py + (size_t)b * (129 * 512);
  float* pb = p + (size_t)b * (129 * 513);
  float last = 0.f;
  float pxc = NEGV, pyc = NEGV;   // prefetched px[s-1][t], py[s][t-1] for next diag
  for (int d = 0; d <= 640; ++d){
    int t = d - s;
    if (s <= 128 && t >= 0 && t <= 512){
      float v = 0.f;
      if (d > 0){
        float up = (s > 0) ? dbuf[(d - 1) & 1][s - 1] + pxc : NEGV;
        float lf = (t > 0) ? dbuf[(d - 1) & 1][s] + pyc : NEGV;
        v = lae(up, lf);
      }
      dbuf[d & 1][s] = v;
      pb[(size_t)s * 513 + t] = v;
      last = v;
    }
    if (s <= 128){ // prefetch operands for diagonal d+1
      int tn = d + 1 - s;
      pxc = (s > 0 && tn >= 0 && tn <= 512) ? pxb[(size_t)(s - 1) * 513 + tn] : NEGV;
      pyc = (tn > 0 && tn <= 512) ? pyb[(size_t)s * 512 + (tn - 1)] : NEGV;
    }
    __syncthreads();
  }
  if (s == 128) tot[b] = last;
}

// ---------- backward DP: occupation-prob grads gpx, gpy ----------
__global__ __launch_bounds__(192) void k_dp_bwd(
    const float* __restrict__ px, const float* __restrict__ py,
    const float* __restrict__ p, const float* __restrict__ tot,
    float* __restrict__ gpx, float* __restrict__ gpy)
{
  int b = blockIdx.x;
  int s = threadIdx.x;
  __shared__ float dbuf[2][132];
  const float* pxb = px + (size_t)b * (128 * 513);
  const float* pyb = py + (size_t)b * (129 * 512);
  const float* pb = p + (size_t)b * (129 * 513);
  float* gxb = gpx + (size_t)b * (128 * 513);
  float* gyb = gpy + (size_t)b * (129 * 512);
  float tv = tot[b];
  if (s < 132){ dbuf[0][s] = NEGV; dbuf[1][s] = NEGV; }
  float pxc = NEGV, pyc = NEGV, pc = 0.f;
  if (s <= 128){
    int t = 640 - s;
    if (t >= 0 && t <= 512){
      pxc = (s < 128) ? pxb[(size_t)s * 513 + t] : NEGV;
      pyc = (t < 512) ? pyb[(size_t)s * 512 + t] : NEGV;
      pc = pb[(size_t)s * 513 + t];
    }
  }
  __syncthreads();
  for (int d = 640; d >= 0; --d){
    int t = d - s;
    if (s <= 128 && t >= 0 && t <= 512){
      float bu = dbuf[(d + 1) & 1][s + 1];   // beta[s+1][t]
      float br = dbuf[(d + 1) & 1][s];       // beta[s][t+1]
      float v;
      if (d == 640) v = 0.f;
      else {
        float aa = (s < 128) ? pxc + bu : NEGV;
        float bb = (t < 512) ? pyc + br : NEGV;
        v = lae(aa, bb);
      }
      if (s < 128) gxb[(size_t)s * 513 + t] = __expf(pc + pxc + bu - tv);
      if (t < 512) gyb[(size_t)s * 512 + t] = __expf(pc + pyc + br - tv);
      dbuf[d & 1][s] = v;
    }
    if (s <= 128){ // prefetch for d-1
      int tn = d - 1 - s;
      if (tn >= 0 && tn <= 512){
        pxc = (s < 128) ? pxb[(size_t)s * 513 + tn] : NEGV;
        pyc = (tn < 512) ? pyb[(size_t)s * 512 + tn] : NEGV;
        pc = pb[(size_t)s * 513 + tn];
      }
    }
    __syncthreads();
  }
}

// ---------- sliding-window argmax over s for each (b,t) ----------
__global__ __launch_bounds__(512) void k_window(
    const float* __restrict__ gpx, const float* __restrict__ gpy, int* __restrict__ sbr)
{
  int b = blockIdx.x;
  int t = threadIdx.x;  // 0..511
  const float* gx = gpx + (size_t)b * (128 * 513);
  const float* gy = gpy + (size_t)b * (129 * 512);
  auto tote = [&](int s) -> float {
    float v = gy[(size_t)s * 512 + t];
    if (s < 128) v += gx[(size_t)s * 513 + t];
    return v;
  };
  float win = 0.f;
  for (int s = 0; s < 19; ++s) win += tote(s);
  float best = win; int arg = 0;
  for (int w = 1; w <= 110; ++w){
    win += tote(w + 18) - tote(w - 1);
    if (win > best){ best = win; arg = w; }   // strict > keeps first-index argmax
  }
  sbr[b * 512 + t] = arg;
}

// ---------- monotone lower-bound adjust (single reverse pass per batch) ----------
__global__ void k_adjust(const int* __restrict__ sbr, int* __restrict__ sbeg){
  if (threadIdx.x != 0) return;
  int b = blockIdx.x;
  const int* in = sbr + b * 512;
  int* out = sbeg + b * 512;
  int sbm = 1 << 30, ym = 1 << 30;
  for (int t = 511; t >= 0; --t){
    sbm = min(sbm, in[t]);
    int y = 18 * t - sbm;
    ym = min(ym, y);
    int yc = ym > 0 ? ym : 0;
    out[t] = 18 * t - yc;
  }
}

// ---------- joiner: H=tanh(am+lm_pruned) bf16, logits=H@Wb+bias, fused logsumexp epilogue ----------
__global__ __launch_bounds__(256) void k_joiner(
    const float* __restrict__ am, const float* __restrict__ lm,
    const int* __restrict__ targets, const float* __restrict__ bias,
    const short* __restrict__ Wb, const int* __restrict__ sbeg,
    float* __restrict__ pxv, float* __restrict__ pyv)
{
  __shared__ short Hs[32][40];          // 32 rows x 32 k, row stride 40 (bank spread)
  __shared__ int rowSym[32];
  __shared__ int rowAm[32];
  __shared__ int rowLm[32];
  __shared__ float redM[32][4];
  __shared__ float redS[32][4];
  __shared__ float rowMax[32];
  __shared__ float rowNorm[32];

  int tid = threadIdx.x;
  int r0 = blockIdx.x * 32;
  if (tid < 32){
    int row = r0 + tid;
    int g = row / 19;
    int j = row - g * 19;
    int b = g >> 9;
    int t = g & 511;
    int start = sbeg[b * 512 + t];
    int sidx = start + j;               // <= 128 by construction
    rowSym[tid] = (sidx < 128) ? targets[b * 128 + sidx] : 0;
    rowAm[tid] = (b * 512 + t) * 512;
    rowLm[tid] = (b * 129 + sidx) * 512;
  }
  __syncthreads();

  int wv = tid >> 6, lane = tid & 63, q = lane >> 4, ln = lane & 15;
  int colBase = wv * 128 + ln;
  int hr = tid >> 3, kk = (tid & 7) * 4;

  floatx4 acc[2][8];
  #pragma unroll
  for (int mt = 0; mt < 2; ++mt)
    #pragma unroll
    for (int nt = 0; nt < 8; ++nt) acc[mt][nt] = (floatx4){0.f, 0.f, 0.f, 0.f};

  for (int k0 = 0; k0 < 512; k0 += 32){
    { // fused activation staging: 4 elems/thread
      const float* ap = am + (size_t)rowAm[hr] + k0 + kk;
      const float* lp = lm + (size_t)rowLm[hr] + k0 + kk;
      floatx4 a4 = *(const floatx4*)ap;
      floatx4 l4 = *(const floatx4*)lp;
      short4v h;
      h[0] = f2bf(fast_tanh(a4[0] + l4[0]));
      h[1] = f2bf(fast_tanh(a4[1] + l4[1]));
      h[2] = f2bf(fast_tanh(a4[2] + l4[2]));
      h[3] = f2bf(fast_tanh(a4[3] + l4[3]));
      *(short4v*)&Hs[hr][kk] = h;
    }
    __syncthreads();
    short8 afr0 = *(const short8*)&Hs[ln][q * 8];
    short8 afr1 = *(const short8*)&Hs[16 + ln][q * 8];
    #pragma unroll
    for (int nt = 0; nt < 8; ++nt){
      int col = colBase + nt * 16;
      short8 bfr = *(const short8*)(Wb + (size_t)col * 512 + k0 + q * 8);
      acc[0][nt] = __builtin_amdgcn_mfma_f32_16x16x32_bf16(afr0, bfr, acc[0][nt], 0, 0, 0);
      acc[1][nt] = __builtin_amdgcn_mfma_f32_16x16x32_bf16(afr1, bfr, acc[1][nt], 0, 0, 0);
    }
    __syncthreads();
  }

  // bias add
  #pragma unroll
  for (int nt = 0; nt < 8; ++nt){
    float bc = bias[colBase + nt * 16];
    #pragma unroll
    for (int mt = 0; mt < 2; ++mt)
      #pragma unroll
      for (int r = 0; r < 4; ++r) acc[mt][nt][r] += bc;
  }
  // per-row max (within quad = 16 lanes holding the 16 cols of each tile)
  #pragma unroll
  for (int mt = 0; mt < 2; ++mt)
    #pragma unroll
    for (int r = 0; r < 4; ++r){
      int row = mt * 16 + q * 4 + r;
      float m = acc[mt][0][r];
      #pragma unroll
      for (int nt = 1; nt < 8; ++nt) m = fmaxf(m, acc[mt][nt][r]);
      m = fmaxf(m, __shfl_xor(m, 1, 16));
      m = fmaxf(m, __shfl_xor(m, 2, 16));
      m = fmaxf(m, __shfl_xor(m, 4, 16));
      m = fmaxf(m, __shfl_xor(m, 8, 16));
      if (ln == 0) redM[row][wv] = m;
    }
  __syncthreads();
  if (tid < 32) rowMax[tid] = fmaxf(fmaxf(redM[tid][0], redM[tid][1]),
                                    fmaxf(redM[tid][2], redM[tid][3]));
  __syncthreads();
  // per-row sum of exp
  #pragma unroll
  for (int mt = 0; mt < 2; ++mt)
    #pragma unroll
    for (int r = 0; r < 4; ++r){
      int row = mt * 16 + q * 4 + r;
      float rm = rowMax[row];
      float sa = 0.f;
      #pragma unroll
      for (int nt = 0; nt < 8; ++nt) sa += __expf(acc[mt][nt][r] - rm);
      sa += __shfl_xor(sa, 1, 16);
      sa += __shfl_xor(sa, 2, 16);
      sa += __shfl_xor(sa, 4, 16);
      sa += __shfl_xor(sa, 8, 16);
      if (ln == 0) redS[row][wv] = sa;
    }
  __syncthreads();
  if (tid < 32) rowNorm[tid] = rowMax[tid] +
      __logf(redS[tid][0] + redS[tid][1] + redS[tid][2] + redS[tid][3]);
  __syncthreads();
  // extract logit[0] and logit[sym]
  #pragma unroll
  for (int mt = 0; mt < 2; ++mt)
    #pragma unroll
    for (int nt = 0; nt < 8; ++nt){
      int col = colBase + nt * 16;
      #pragma unroll
      for (int r = 0; r < 4; ++r){
        int row = mt * 16 + q * 4 + r;
        float v = acc[mt][nt][r] - rowNorm[row];
        int gr = r0 + row;
        if (col == 0) pyv[gr] = v;
        if (col == rowSym[row]) pxv[gr] = v;
      }
    }
}

// ---------- scatter band values into full px2 (B,S,T+1) / py2 (B,S+1,T) ----------
__global__ __launch_bounds__(256) void k_band(
    const float* __restrict__ pxv, const float* __restrict__ pyv,
    const int* __restrict__ sbeg, float* __restrict__ px2, float* __restrict__ py2)
{
  size_t idx = (size_t)blockIdx.x * 256 + threadIdx.x;
  if (idx >= (size_t)8 * 129 * 513) return;
  int b = idx / (129 * 513);
  int rem = idx % (129 * 513);
  int s = rem / 513, t = rem % 513;
  if (t < 512){
    int start = sbeg[b * 512 + t];
    int j = s - start;
    bool in = (j >= 0 && j < 19);
    py2[((size_t)(b * 129 + s)) * 512 + t] = in ? pyv[((size_t)(b * 512 + t)) * 19 + j] : NEGV;
    if (s < 128)
      px2[((size_t)(b * 128 + s)) * 513 + t] = in ? pxv[((size_t)(b * 512 + t)) * 19 + j] : NEGV;
  } else if (s < 128){
    px2[((size_t)(b * 128 + s)) * 513 + t] = NEGV;
  }
}

// ---------- final scalar ----------
__global__ void k_final(const float* __restrict__ tots, const float* __restrict__ totp,
                        float* __restrict__ out){
  if (blockIdx.x == 0 && threadIdx.x == 0){
    float a = 0.f, c = 0.f;
    for (int i = 0; i < 8; ++i){ a += tots[i]; c += totp[i]; }
    out[0] = -0.1f * (a * 0.125f) - (c * 0.125f);
  }
}

extern "C" void kernel_launch(void* const* d_in, const int* in_sizes, int n_in,
                              void* d_out, int out_size, void* d_ws, size_t ws_size,
                              hipStream_t stream){
  (void)in_sizes; (void)n_in; (void)out_size; (void)ws_size;
  const float* am      = (const float*)d_in[0];
  const float* lm      = (const float*)d_in[1];
  const int*   targets = (const int*)d_in[2];
  const float* W       = (const float*)d_in[4];
  const float* bias    = (const float*)d_in[5];
  float* out = (float*)d_out;

  char* base = (char*)d_ws;
  size_t off = 0;
  auto alloc = [&](size_t bytes) -> char* {
    char* r = base + off;
    off += (bytes + 255) & ~(size_t)255;
    return r;
  };
  float* amMax = (float*)alloc(8ull * 512 * 4);
  float* lmMax = (float*)alloc(8ull * 129 * 4);
  float* lmLse = (float*)alloc(8ull * 129 * 4);
  float* normv = (float*)alloc(8ull * 129 * 512 * 4);
  float* px    = (float*)alloc(8ull * 128 * 513 * 4);
  float* py    = (float*)alloc(8ull * 129 * 512 * 4);
  float* pmat  = (float*)alloc(8ull * 129 * 513 * 4);
  float* gpx   = (float*)alloc(8ull * 128 * 513 * 4);
  float* gpy   = (float*)alloc(8ull * 129 * 512 * 4);
  float* tots  = (float*)alloc(8 * 4);
  float* totp  = (float*)alloc(8 * 4);
  int*   sbr   = (int*)alloc(8ull * 512 * 4);
  int*   sbeg  = (int*)alloc(8ull * 512 * 4);
  float* pxv   = (float*)alloc(8ull * 512 * 19 * 4);
  float* pyv   = (float*)alloc(8ull * 512 * 19 * 4);
  float* px2   = (float*)alloc(8ull * 128 * 513 * 4);
  float* py2   = (float*)alloc(8ull * 129 * 512 * 4);
  short* Wb    = (short*)alloc(512ull * 512 * 2);

  k_row_stats<<<dim3(4096), dim3(256), 0, stream>>>(am, amMax, (float*)nullptr);
  k_row_stats<<<dim3(1032), dim3(256), 0, stream>>>(lm, lmMax, lmLse);
  k_wb<<<dim3(1024), dim3(256), 0, stream>>>(W, Wb);
  k_norm<<<dim3(4, 9, 8), dim3(256), 0, stream>>>(am, lm, lmMax, amMax, normv);
  k_pxpy<<<dim3(1032), dim3(256), 0, stream>>>(am, lm, targets, normv, lmLse, px, py);
  k_dp_fwd<<<dim3(8), dim3(192), 0, stream>>>(px, py, pmat, tots);
  k_dp_bwd<<<dim3(8), dim3(192), 0, stream>>>(px, py, pmat, tots, gpx, gpy);
  k_window<<<dim3(8), dim3(512), 0, stream>>>(gpx, gpy, sbr);
  k_adjust<<<dim3(8), dim3(64), 0, stream>>>(sbr, sbeg);
  k_joiner<<<dim3(2432), dim3(256), 0, stream>>>(am, lm, targets, bias, Wb, sbeg, pxv, pyv);
  k_band<<<dim3(2069), dim3(256), 0, stream>>>(pxv, pyv, sbeg, px2, py2);
  k_dp_fwd<<<dim3(8), dim3(192), 0, stream>>>(px2, py2, pmat, totp);
  k_final<<<dim3(1), dim3(64), 0, stream>>>(tots, totp, out);
}

// Round 2
// 1494.064 us; speedup vs baseline: 1.2404x; 1.2404x over previous
//
#include <hip/hip_runtime.h>
#include <math.h>

#define NEGV -1e20f

typedef __attribute__((ext_vector_type(4))) float floatx4;
typedef __attribute__((ext_vector_type(8))) short short8;
typedef __attribute__((ext_vector_type(4))) short short4v;

// B=8, T=512, S=128, C=512, S1=129, T1=513, R=19 (hard-coded for this problem)

__device__ __forceinline__ float lae(float a, float b){
  float mx = fmaxf(a, b);
  float mn = fminf(a, b);
  return mx + log1pf(__expf(mn - mx));   // exp underflows to 0 for big gaps -> exact
}

__device__ __forceinline__ short f2bf(float x){  // f32 -> bf16 RNE
  union { float f; unsigned u; } v; v.f = x;
  unsigned r = v.u + 0x7fffu + ((v.u >> 16) & 1u);
  return (short)(r >> 16);
}

__device__ __forceinline__ float fast_tanh(float x){
  x = fminf(fmaxf(x, -15.f), 15.f);
  float e = __expf(2.f * x);
  return (e - 1.f) / (e + 1.f);
}

// ---------- per-row max (+ optional logsumexp) over C=512 ----------
__global__ __launch_bounds__(256) void k_row_stats(
    const float* __restrict__ in, float* __restrict__ outMax, float* __restrict__ outLse)
{
  int row = blockIdx.x;
  const float* r = in + (size_t)row * 512;
  int tid = threadIdx.x;
  float v0 = r[tid], v1 = r[tid + 256];
  float m = fmaxf(v0, v1);
  #pragma unroll
  for (int off = 32; off; off >>= 1) m = fmaxf(m, __shfl_xor(m, off, 64));
  __shared__ float sm[4];
  __shared__ float sbm;
  int wv = tid >> 6;
  if ((tid & 63) == 0) sm[wv] = m;
  __syncthreads();
  if (tid == 0) sbm = fmaxf(fmaxf(sm[0], sm[1]), fmaxf(sm[2], sm[3]));
  __syncthreads();
  float mx = sbm;
  if (tid == 0) outMax[row] = mx;
  if (outLse){
    float s = __expf(v0 - mx) + __expf(v1 - mx);
    #pragma unroll
    for (int off = 32; off; off >>= 1) s += __shfl_xor(s, off, 64);
    __shared__ float sp[4];
    if ((tid & 63) == 0) sp[wv] = s;
    __syncthreads();
    if (tid == 0) outLse[row] = mx + __logf(sp[0] + sp[1] + sp[2] + sp[3]);
  }
}

// ---------- transpose + bf16-convert joiner_w: Wb[d][c] = bf16(W[c][d]) ----------
__global__ __launch_bounds__(256) void k_wb(const float* __restrict__ W, short* __restrict__ Wb){
  int idx = blockIdx.x * 256 + threadIdx.x;   // 262144 total
  int d = idx >> 9, c = idx & 511;
  Wb[idx] = f2bf(W[c * 512 + d]);
}

// ---------- normalizers: norm[b,s,t] = log(dot(exp(lm-lmmax), exp(am-ammax))) + maxes ----------
__global__ __launch_bounds__(256) void k_norm(
    const float* __restrict__ am, const float* __restrict__ lm,
    const float* __restrict__ lmMax, const float* __restrict__ amMax,
    float* __restrict__ normv)
{
  int b = blockIdx.z;
  int s0 = blockIdx.y * 16;
  int t0 = blockIdx.x * 128;
  __shared__ float lmS[16][68];
  __shared__ float amS[128][68];
  int tid = threadIdx.x;
  int ts = tid >> 4, tt = tid & 15;
  float acc[8];
  #pragma unroll
  for (int j = 0; j < 8; ++j) acc[j] = 0.f;

  for (int k0 = 0; k0 < 512; k0 += 64){
    { // stage lm tile 16x64 (exp fused)
      int e = tid * 4;
      int rr = e >> 6, cc = e & 63;
      int s = s0 + rr;
      floatx4 o = {0.f, 0.f, 0.f, 0.f};
      if (s < 129){
        float mx = lmMax[b * 129 + s];
        floatx4 v = *(const floatx4*)(lm + ((size_t)(b * 129 + s)) * 512 + k0 + cc);
        o[0] = __expf(v[0] - mx); o[1] = __expf(v[1] - mx);
        o[2] = __expf(v[2] - mx); o[3] = __expf(v[3] - mx);
      }
      *(floatx4*)&lmS[rr][cc] = o;
    }
    #pragma unroll
    for (int i = 0; i < 8; ++i){ // stage am tile 128x64 (exp fused)
      int e = (tid + i * 256) * 4;
      int rr = e >> 6, cc = e & 63;
      float mx = amMax[b * 512 + t0 + rr];
      floatx4 v = *(const floatx4*)(am + ((size_t)(b * 512 + t0 + rr)) * 512 + k0 + cc);
      floatx4 o;
      o[0] = __expf(v[0] - mx); o[1] = __expf(v[1] - mx);
      o[2] = __expf(v[2] - mx); o[3] = __expf(v[3] - mx);
      *(floatx4*)&amS[rr][cc] = o;
    }
    __syncthreads();
    #pragma unroll 4
    for (int k = 0; k < 64; ++k){
      float a = lmS[ts][k];
      #pragma unroll
      for (int j = 0; j < 8; ++j) acc[j] += a * amS[tt + 16 * j][k];
    }
    __syncthreads();
  }
  int s = s0 + ts;
  if (s < 129){
    float lmx = lmMax[b * 129 + s];
    #pragma unroll
    for (int j = 0; j < 8; ++j){
      int t = t0 + tt + 16 * j;
      normv[((size_t)(b * 129 + s)) * 512 + t] = __logf(acc[j]) + lmx + amMax[b * 512 + t];
    }
  }
}

// ---------- smoothed px (B,S,T+1) and py (B,S+1,T) ----------
__global__ __launch_bounds__(256) void k_pxpy(
    const float* __restrict__ am, const float* __restrict__ lm,
    const int* __restrict__ targets, const float* __restrict__ normv,
    const float* __restrict__ lmLse, float* __restrict__ px, float* __restrict__ py)
{
  int bs = blockIdx.x;           // b*129 + s
  int b = bs / 129, s = bs % 129;
  float lm0 = lm[(size_t)bs * 512];
  float lse = lmLse[bs];
  int sym = 0; float lms = 0.f;
  if (s < 128){ sym = targets[b * 128 + s]; lms = lm[(size_t)bs * 512 + sym]; }
  const float* nrm = normv + (size_t)bs * 512;
  float* pyr = py + (size_t)bs * 512;
  float* pxr = px + (size_t)(b * 128 + s) * 513;   // only used when s<128
  for (int t = threadIdx.x; t < 513; t += 256){
    if (t < 512){
      float n = nrm[t];
      float a0 = am[((size_t)(b * 512 + t)) * 512];
      pyr[t] = 0.75f * (a0 + lm0 - n) + 0.25f * (lm0 - lse);
      if (s < 128){
        float as = am[((size_t)(b * 512 + t)) * 512 + sym];
        pxr[t] = 0.75f * (as + lms - n) + 0.25f * (lms - lse);
      }
    } else if (s < 128){
      pxr[t] = NEGV;
    }
  }
}

// ======================================================================
// Wave-systolic lattice DP.
// 3 waves x 43 rows per batch. lane = local row. Diagonal sweep: at local
// step dl, lane l handles t = dl - l (fwd) / t = 554 - dl - l (bwd).
// p[s-1][t] (resp. beta[s+1][t]) travels lane-to-lane via ds_bpermute.
// Band boundary rows cross waves through LDS with a 2-round skew
// (C=64 steps/round >= 42-step intra-band lag => disjoint r/w windows).
// px/py/alpha are streamed per-lane via register double-buffers of 8,
// prefetched one block ahead (global latency off the serial chain).
// ======================================================================

__global__ __launch_bounds__(192) void k_dp_fwd(
    const float* __restrict__ px, const float* __restrict__ py,
    float* __restrict__ p, float* __restrict__ tot)
{
  int b = blockIdx.x;
  int tid = threadIdx.x;
  int w = tid >> 6, l = tid & 63;
  int s = 43 * w + l;
  bool act = (l < 43);
  bool haspx = act && (s >= 1);
  __shared__ float bnd[2][576];     // bnd[j][t] = p[43j+42][t], written by wave j lane 42
  const float* pxrow = px + (size_t)b * (128 * 513) + (size_t)(s - 1) * 513;
  const float* pyrow = py + (size_t)b * (129 * 512) + (size_t)s * 512;
  float* prow = p + (size_t)b * (129 * 513) + (size_t)s * 513;
  bool pstore = (p != nullptr);
  float cur = 0.f;
  float pxb[2][8], pyb[2][8];
  int paddr = (l - 1) << 2;

  auto LOADB = [&](int dl0, float* pxd, float* pyd){
    #pragma unroll
    for (int k = 0; k < 8; ++k){
      int t = dl0 + k - l;
      pxd[k] = (haspx && t >= 0 && t <= 512) ? pxrow[t] : NEGV;
      pyd[k] = (act && t >= 1 && t <= 512) ? pyrow[t - 1] : NEGV;
    }
  };
  LOADB(0, pxb[0], pyb[0]);

  for (int r = 0; r < 13; ++r){
    if (r >= 2 * w && r < 2 * w + 9){
      int base = (r - 2 * w) * 64;
      #pragma unroll
      for (int blk = 0; blk < 8; ++blk){
        const int cb = blk & 1, nb = cb ^ 1;
        int dl0 = base + blk * 8;
        LOADB(dl0 + 8, pxb[nb], pyb[nb]);
        float bndv[8];
        {
          bool rd = (w > 0 && l == 0);
          #pragma unroll
          for (int k = 0; k < 8; ++k)
            bndv[k] = rd ? bnd[w - 1][dl0 + k] : NEGV;
        }
        #pragma unroll
        for (int k = 0; k < 8; ++k){
          int t = dl0 + k - l;
          float upv = __int_as_float(
              __builtin_amdgcn_ds_bpermute(paddr, __float_as_int(cur)));
          if (l == 0) upv = bndv[k];
          float aa = upv + pxb[cb][k];
          float bb = cur + pyb[cb][k];
          float nv = lae(aa, bb);
          if (s == 0 && t == 0) nv = 0.f;
          if (act && t >= 0 && t <= 512){
            cur = nv;
            if (pstore) prow[t] = cur;
            if (l == 42 && w < 2) bnd[w][t] = cur;
            if (s == 128 && t == 512) tot[b] = cur;
          }
        }
      }
    }
    __syncthreads();
  }
}

__global__ __launch_bounds__(192) void k_dp_bwd(
    const float* __restrict__ px, const float* __restrict__ py,
    const float* __restrict__ p, const float* __restrict__ tot,
    float* __restrict__ gpx, float* __restrict__ gpy)
{
  int b = blockIdx.x;
  int tid = threadIdx.x;
  int w = tid >> 6, l = tid & 63;
  int s = 43 * w + l;
  bool act = (l < 43);
  bool haspx = act && (s < 128);
  __shared__ float bnd[2][576];     // bnd[j][t] = beta[43(j+1)][t], written by wave j+1 lane 0
  const float* pxrow = px + (size_t)b * (128 * 513) + (size_t)s * 513;
  const float* pyrow = py + (size_t)b * (129 * 512) + (size_t)s * 512;
  const float* parow = p + (size_t)b * (129 * 513) + (size_t)s * 513;
  float* gxrow = gpx + (size_t)b * (128 * 513) + (size_t)s * 513;
  float* gyrow = gpy + (size_t)b * (129 * 512) + (size_t)s * 512;
  float tv = tot[b];
  float cur = 0.f;
  float pxb[2][8], pyb[2][8], pab[2][8];
  int paddr = (l + 1) << 2;
  int r0 = 2 * (2 - w);

  auto LOADB = [&](int dl0, float* pxd, float* pyd, float* pad){
    #pragma unroll
    for (int k = 0; k < 8; ++k){
      int t = 554 - (dl0 + k) - l;
      pxd[k] = (haspx && t >= 0 && t <= 512) ? pxrow[t] : NEGV;
      pyd[k] = (act && t >= 0 && t <= 511) ? pyrow[t] : NEGV;
      pad[k] = (act && t >= 0 && t <= 512) ? parow[t] : 0.f;
    }
  };
  LOADB(0, pxb[0], pyb[0], pab[0]);

  for (int r = 0; r < 13; ++r){
    if (r >= r0 && r < r0 + 9){
      int base = (r - r0) * 64;
      #pragma unroll
      for (int blk = 0; blk < 8; ++blk){
        const int cb = blk & 1, nb = cb ^ 1;
        int dl0 = base + blk * 8;
        LOADB(dl0 + 8, pxb[nb], pyb[nb], pab[nb]);
        float bndv[8];
        {
          bool rd = (w < 2 && l == 42);
          #pragma unroll
          for (int k = 0; k < 8; ++k){
            int ttv = 512 - dl0 - k;
            int idx = ttv < 0 ? 0 : ttv;
            bndv[k] = rd ? bnd[w][idx] : NEGV;
          }
        }
        #pragma unroll
        for (int k = 0; k < 8; ++k){
          int t = 554 - (dl0 + k) - l;
          float dnv = __int_as_float(
              __builtin_amdgcn_ds_bpermute(paddr, __float_as_int(cur)));
          if (l == 42) dnv = bndv[k];
          float aa = pxb[cb][k] + dnv;   // px[s][t] + beta[s+1][t]
          float bb = pyb[cb][k] + cur;   // py[s][t] + beta[s][t+1]
          float nv = lae(aa, bb);
          if (s == 128 && t == 512) nv = 0.f;
          if (act && t >= 0 && t <= 512){
            float pa = pab[cb][k];
            if (s < 128) gxrow[t] = __expf(pa + aa - tv);
            if (t < 512) gyrow[t] = __expf(pa + bb - tv);
            cur = nv;
            if (l == 0 && w > 0) bnd[w - 1][t] = cur;
          }
        }
      }
    }
    __syncthreads();
  }
}

// ---------- sliding-window argmax over s for each (b,t) ----------
__global__ __launch_bounds__(512) void k_window(
    const float* __restrict__ gpx, const float* __restrict__ gpy, int* __restrict__ sbr)
{
  int b = blockIdx.x;
  int t = threadIdx.x;  // 0..511
  const float* gx = gpx + (size_t)b * (128 * 513);
  const float* gy = gpy + (size_t)b * (129 * 512);
  auto tote = [&](int s) -> float {
    float v = gy[(size_t)s * 512 + t];
    if (s < 128) v += gx[(size_t)s * 513 + t];
    return v;
  };
  float win = 0.f;
  for (int s = 0; s < 19; ++s) win += tote(s);
  float best = win; int arg = 0;
  for (int w = 1; w <= 110; ++w){
    win += tote(w + 18) - tote(w - 1);
    if (win > best){ best = win; arg = w; }   // strict > keeps first-index argmax
  }
  sbr[b * 512 + t] = arg;
}

// ---------- monotone lower-bound adjust (single reverse pass per batch) ----------
__global__ void k_adjust(const int* __restrict__ sbr, int* __restrict__ sbeg){
  if (threadIdx.x != 0) return;
  int b = blockIdx.x;
  const int* in = sbr + b * 512;
  int* out = sbeg + b * 512;
  int sbm = 1 << 30, ym = 1 << 30;
  for (int t = 511; t >= 0; --t){
    sbm = min(sbm, in[t]);
    int y = 18 * t - sbm;
    ym = min(ym, y);
    int yc = ym > 0 ? ym : 0;
    out[t] = 18 * t - yc;
  }
}

// ---------- joiner: H=tanh(am+lm_pruned) bf16, logits=H@Wb+bias, fused logsumexp epilogue ----------
__global__ __launch_bounds__(256) void k_joiner(
    const float* __restrict__ am, const float* __restrict__ lm,
    const int* __restrict__ targets, const float* __restrict__ bias,
    const short* __restrict__ Wb, const int* __restrict__ sbeg,
    float* __restrict__ pxv, float* __restrict__ pyv)
{
  __shared__ short Hs[32][40];          // 32 rows x 32 k, row stride 40 (bank spread)
  __shared__ int rowSym[32];
  __shared__ int rowAm[32];
  __shared__ int rowLm[32];
  __shared__ float redM[32][4];
  __shared__ float redS[32][4];
  __shared__ float rowMax[32];
  __shared__ float rowNorm[32];

  int tid = threadIdx.x;
  int r0 = blockIdx.x * 32;
  if (tid < 32){
    int row = r0 + tid;
    int g = row / 19;
    int j = row - g * 19;
    int b = g >> 9;
    int t = g & 511;
    int start = sbeg[b * 512 + t];
    int sidx = start + j;               // <= 128 by construction
    rowSym[tid] = (sidx < 128) ? targets[b * 128 + sidx] : 0;
    rowAm[tid] = (b * 512 + t) * 512;
    rowLm[tid] = (b * 129 + sidx) * 512;
  }
  __syncthreads();

  int wv = tid >> 6, lane = tid & 63, q = lane >> 4, ln = lane & 15;
  int colBase = wv * 128 + ln;
  int hr = tid >> 3, kk = (tid & 7) * 4;

  floatx4 acc[2][8];
  #pragma unroll
  for (int mt = 0; mt < 2; ++mt)
    #pragma unroll
    for (int nt = 0; nt < 8; ++nt) acc[mt][nt] = (floatx4){0.f, 0.f, 0.f, 0.f};

  for (int k0 = 0; k0 < 512; k0 += 32){
    { // fused activation staging: 4 elems/thread
      const float* ap = am + (size_t)rowAm[hr] + k0 + kk;
      const float* lp = lm + (size_t)rowLm[hr] + k0 + kk;
      floatx4 a4 = *(const floatx4*)ap;
      floatx4 l4 = *(const floatx4*)lp;
      short4v h;
      h[0] = f2bf(fast_tanh(a4[0] + l4[0]));
      h[1] = f2bf(fast_tanh(a4[1] + l4[1]));
      h[2] = f2bf(fast_tanh(a4[2] + l4[2]));
      h[3] = f2bf(fast_tanh(a4[3] + l4[3]));
      *(short4v*)&Hs[hr][kk] = h;
    }
    __syncthreads();
    short8 afr0 = *(const short8*)&Hs[ln][q * 8];
    short8 afr1 = *(const short8*)&Hs[16 + ln][q * 8];
    #pragma unroll
    for (int nt = 0; nt < 8; ++nt){
      int col = colBase + nt * 16;
      short8 bfr = *(const short8*)(Wb + (size_t)col * 512 + k0 + q * 8);
      acc[0][nt] = __builtin_amdgcn_mfma_f32_16x16x32_bf16(afr0, bfr, acc[0][nt], 0, 0, 0);
      acc[1][nt] = __builtin_amdgcn_mfma_f32_16x16x32_bf16(afr1, bfr, acc[1][nt], 0, 0, 0);
    }
    __syncthreads();
  }

  // bias add
  #pragma unroll
  for (int nt = 0; nt < 8; ++nt){
    float bc = bias[colBase + nt * 16];
    #pragma unroll
    for (int mt = 0; mt < 2; ++mt)
      #pragma unroll
      for (int r = 0; r < 4; ++r) acc[mt][nt][r] += bc;
  }
  // per-row max (within quad = 16 lanes holding the 16 cols of each tile)
  #pragma unroll
  for (int mt = 0; mt < 2; ++mt)
    #pragma unroll
    for (int r = 0; r < 4; ++r){
      int row = mt * 16 + q * 4 + r;
      float m = acc[mt][0][r];
      #pragma unroll
      for (int nt = 1; nt < 8; ++nt) m = fmaxf(m, acc[mt][nt][r]);
      m = fmaxf(m, __shfl_xor(m, 1, 16));
      m = fmaxf(m, __shfl_xor(m, 2, 16));
      m = fmaxf(m, __shfl_xor(m, 4, 16));
      m = fmaxf(m, __shfl_xor(m, 8, 16));
      if (ln == 0) redM[row][wv] = m;
    }
  __syncthreads();
  if (tid < 32) rowMax[tid] = fmaxf(fmaxf(redM[tid][0], redM[tid][1]),
                                    fmaxf(redM[tid][2], redM[tid][3]));
  __syncthreads();
  // per-row sum of exp
  #pragma unroll
  for (int mt = 0; mt < 2; ++mt)
    #pragma unroll
    for (int r = 0; r < 4; ++r){
      int row = mt * 16 + q * 4 + r;
      float rm = rowMax[row];
      float sa = 0.f;
      #pragma unroll
      for (int nt = 0; nt < 8; ++nt) sa += __expf(acc[mt][nt][r] - rm);
      sa += __shfl_xor(sa, 1, 16);
      sa += __shfl_xor(sa, 2, 16);
      sa += __shfl_xor(sa, 4, 16);
      sa += __shfl_xor(sa, 8, 16);
      if (ln == 0) redS[row][wv] = sa;
    }
  __syncthreads();
  if (tid < 32) rowNorm[tid] = rowMax[tid] +
      __logf(redS[tid][0] + redS[tid][1] + redS[tid][2] + redS[tid][3]);
  __syncthreads();
  // extract logit[0] and logit[sym]
  #pragma unroll
  for (int mt = 0; mt < 2; ++mt)
    #pragma unroll
    for (int nt = 0; nt < 8; ++nt){
      int col = colBase + nt * 16;
      #pragma unroll
      for (int r = 0; r < 4; ++r){
        int row = mt * 16 + q * 4 + r;
        float v = acc[mt][nt][r] - rowNorm[row];
        int gr = r0 + row;
        if (col == 0) pyv[gr] = v;
        if (col == rowSym[row]) pxv[gr] = v;
      }
    }
}

// ---------- scatter band values into full px2 (B,S,T+1) / py2 (B,S+1,T) ----------
__global__ __launch_bounds__(256) void k_band(
    const float* __restrict__ pxv, const float* __restrict__ pyv,
    const int* __restrict__ sbeg, float* __restrict__ px2, float* __restrict__ py2)
{
  size_t idx = (size_t)blockIdx.x * 256 + threadIdx.x;
  if (idx >= (size_t)8 * 129 * 513) return;
  int b = idx / (129 * 513);
  int rem = idx % (129 * 513);
  int s = rem / 513, t = rem % 513;
  if (t < 512){
    int start = sbeg[b * 512 + t];
    int j = s - start;
    bool in = (j >= 0 && j < 19);
    py2[((size_t)(b * 129 + s)) * 512 + t] = in ? pyv[((size_t)(b * 512 + t)) * 19 + j] : NEGV;
    if (s < 128)
      px2[((size_t)(b * 128 + s)) * 513 + t] = in ? pxv[((size_t)(b * 512 + t)) * 19 + j] : NEGV;
  } else if (s < 128){
    px2[((size_t)(b * 128 + s)) * 513 + t] = NEGV;
  }
}

// ---------- final scalar ----------
__global__ void k_final(const float* __restrict__ tots, const float* __restrict__ totp,
                        float* __restrict__ out){
  if (blockIdx.x == 0 && threadIdx.x == 0){
    float a = 0.f, c = 0.f;
    for (int i = 0; i < 8; ++i){ a += tots[i]; c += totp[i]; }
    out[0] = -0.1f * (a * 0.125f) - (c * 0.125f);
  }
}

extern "C" void kernel_launch(void* const* d_in, const int* in_sizes, int n_in,
                              void* d_out, int out_size, void* d_ws, size_t ws_size,
                              hipStream_t stream){
  (void)in_sizes; (void)n_in; (void)out_size; (void)ws_size;
  const float* am      = (const float*)d_in[0];
  const float* lm      = (const float*)d_in[1];
  const int*   targets = (const int*)d_in[2];
  const float* W       = (const float*)d_in[4];
  const float* bias    = (const float*)d_in[5];
  float* out = (float*)d_out;

  char* base = (char*)d_ws;
  size_t off = 0;
  auto alloc = [&](size_t bytes) -> char* {
    char* r = base + off;
    off += (bytes + 255) & ~(size_t)255;
    return r;
  };
  float* amMax = (float*)alloc(8ull * 512 * 4);
  float* lmMax = (float*)alloc(8ull * 129 * 4);
  float* lmLse = (float*)alloc(8ull * 129 * 4);
  float* normv = (float*)alloc(8ull * 129 * 512 * 4);
  float* px    = (float*)alloc(8ull * 128 * 513 * 4);
  float* py    = (float*)alloc(8ull * 129 * 512 * 4);
  float* pmat  = (float*)alloc(8ull * 129 * 513 * 4);
  float* gpx   = (float*)alloc(8ull * 128 * 513 * 4);
  float* gpy   = (float*)alloc(8ull * 129 * 512 * 4);
  float* tots  = (float*)alloc(8 * 4);
  float* totp  = (float*)alloc(8 * 4);
  int*   sbr   = (int*)alloc(8ull * 512 * 4);
  int*   sbeg  = (int*)alloc(8ull * 512 * 4);
  float* pxv   = (float*)alloc(8ull * 512 * 19 * 4);
  float* pyv   = (float*)alloc(8ull * 512 * 19 * 4);
  float* px2   = (float*)alloc(8ull * 128 * 513 * 4);
  float* py2   = (float*)alloc(8ull * 129 * 512 * 4);
  short* Wb    = (short*)alloc(512ull * 512 * 2);

  k_row_stats<<<dim3(4096), dim3(256), 0, stream>>>(am, amMax, (float*)nullptr);
  k_row_stats<<<dim3(1032), dim3(256), 0, stream>>>(lm, lmMax, lmLse);
  k_wb<<<dim3(1024), dim3(256), 0, stream>>>(W, Wb);
  k_norm<<<dim3(4, 9, 8), dim3(256), 0, stream>>>(am, lm, lmMax, amMax, normv);
  k_pxpy<<<dim3(1032), dim3(256), 0, stream>>>(am, lm, targets, normv, lmLse, px, py);
  k_dp_fwd<<<dim3(8), dim3(192), 0, stream>>>(px, py, pmat, tots);
  k_dp_bwd<<<dim3(8), dim3(192), 0, stream>>>(px, py, pmat, tots, gpx, gpy);
  k_window<<<dim3(8), dim3(512), 0, stream>>>(gpx, gpy, sbr);
  k_adjust<<<dim3(8), dim3(64), 0, stream>>>(sbr, sbeg);
  k_joiner<<<dim3(2432), dim3(256), 0, stream>>>(am, lm, targets, bias, Wb, sbeg, pxv, pyv);
  k_band<<<dim3(2069), dim3(256), 0, stream>>>(pxv, pyv, sbeg, px2, py2);
  k_dp_fwd<<<dim3(8), dim3(192), 0, stream>>>(px2, py2, (float*)nullptr, totp);
  k_final<<<dim3(1), dim3(64), 0, stream>>>(tots, totp, out);
}

// Round 3
// 1021.261 us; speedup vs baseline: 1.8147x; 1.4630x over previous
//
#include <hip/hip_runtime.h>
#include <math.h>

#define NEGV -1e20f
#define DPAD 132   // diag row stride (s index), 16B-aligned

typedef __attribute__((ext_vector_type(4))) float floatx4;
typedef __attribute__((ext_vector_type(8))) short short8;
typedef __attribute__((ext_vector_type(4))) short short4v;

// B=8, T=512, S=128, C=512, S1=129, T1=513, R=19 (hard-coded for this problem)
// Diagonal-major DP arrays: X[b][d][s] = x[s][t] with d = s+t.
//   pxd/pyd/gxd/gyd: 640 x DPAD rows per batch; pd (alpha): 641 x DPAD.

__device__ __forceinline__ float lae(float a, float b){
  float mx = fmaxf(a, b);
  float mn = fminf(a, b);
  return mx + __logf(1.f + __expf(mn - mx));   // exp underflows to 0 for big gaps
}

__device__ __forceinline__ short f2bf(float x){  // f32 -> bf16 RNE
  union { float f; unsigned u; } v; v.f = x;
  unsigned r = v.u + 0x7fffu + ((v.u >> 16) & 1u);
  return (short)(r >> 16);
}

__device__ __forceinline__ float fast_tanh(float x){
  x = fminf(fmaxf(x, -15.f), 15.f);
  float e = __expf(2.f * x);
  return (e - 1.f) / (e + 1.f);
}

// ---------- per-row max (+ optional logsumexp) over C=512 ----------
__global__ __launch_bounds__(256) void k_row_stats(
    const float* __restrict__ in, float* __restrict__ outMax, float* __restrict__ outLse)
{
  int row = blockIdx.x;
  const float* r = in + (size_t)row * 512;
  int tid = threadIdx.x;
  float v0 = r[tid], v1 = r[tid + 256];
  float m = fmaxf(v0, v1);
  #pragma unroll
  for (int off = 32; off; off >>= 1) m = fmaxf(m, __shfl_xor(m, off, 64));
  __shared__ float sm[4];
  __shared__ float sbm;
  int wv = tid >> 6;
  if ((tid & 63) == 0) sm[wv] = m;
  __syncthreads();
  if (tid == 0) sbm = fmaxf(fmaxf(sm[0], sm[1]), fmaxf(sm[2], sm[3]));
  __syncthreads();
  float mx = sbm;
  if (tid == 0) outMax[row] = mx;
  if (outLse){
    float s = __expf(v0 - mx) + __expf(v1 - mx);
    #pragma unroll
    for (int off = 32; off; off >>= 1) s += __shfl_xor(s, off, 64);
    __shared__ float sp[4];
    if ((tid & 63) == 0) sp[wv] = s;
    __syncthreads();
    if (tid == 0) outLse[row] = mx + __logf(sp[0] + sp[1] + sp[2] + sp[3]);
  }
}

// ---------- transpose + bf16-convert joiner_w: Wb[d][c] = bf16(W[c][d]) ----------
__global__ __launch_bounds__(256) void k_wb(const float* __restrict__ W, short* __restrict__ Wb){
  int idx = blockIdx.x * 256 + threadIdx.x;   // 262144 total
  int d = idx >> 9, c = idx & 511;
  Wb[idx] = f2bf(W[c * 512 + d]);
}

// ---------- normalizers: norm[b,s,t] = log(dot(exp(lm-lmmax), exp(am-ammax))) + maxes ----------
__global__ __launch_bounds__(256) void k_norm(
    const float* __restrict__ am, const float* __restrict__ lm,
    const float* __restrict__ lmMax, const float* __restrict__ amMax,
    float* __restrict__ normv)
{
  int b = blockIdx.z;
  int s0 = blockIdx.y * 16;
  int t0 = blockIdx.x * 128;
  __shared__ float lmS[16][68];
  __shared__ float amS[128][68];
  int tid = threadIdx.x;
  int ts = tid >> 4, tt = tid & 15;
  float acc[8];
  #pragma unroll
  for (int j = 0; j < 8; ++j) acc[j] = 0.f;

  for (int k0 = 0; k0 < 512; k0 += 64){
    { // stage lm tile 16x64 (exp fused)
      int e = tid * 4;
      int rr = e >> 6, cc = e & 63;
      int s = s0 + rr;
      floatx4 o = {0.f, 0.f, 0.f, 0.f};
      if (s < 129){
        float mx = lmMax[b * 129 + s];
        floatx4 v = *(const floatx4*)(lm + ((size_t)(b * 129 + s)) * 512 + k0 + cc);
        o[0] = __expf(v[0] - mx); o[1] = __expf(v[1] - mx);
        o[2] = __expf(v[2] - mx); o[3] = __expf(v[3] - mx);
      }
      *(floatx4*)&lmS[rr][cc] = o;
    }
    #pragma unroll
    for (int i = 0; i < 8; ++i){ // stage am tile 128x64 (exp fused)
      int e = (tid + i * 256) * 4;
      int rr = e >> 6, cc = e & 63;
      float mx = amMax[b * 512 + t0 + rr];
      floatx4 v = *(const floatx4*)(am + ((size_t)(b * 512 + t0 + rr)) * 512 + k0 + cc);
      floatx4 o;
      o[0] = __expf(v[0] - mx); o[1] = __expf(v[1] - mx);
      o[2] = __expf(v[2] - mx); o[3] = __expf(v[3] - mx);
      *(floatx4*)&amS[rr][cc] = o;
    }
    __syncthreads();
    #pragma unroll 4
    for (int k = 0; k < 64; ++k){
      float a = lmS[ts][k];
      #pragma unroll
      for (int j = 0; j < 8; ++j) acc[j] += a * amS[tt + 16 * j][k];
    }
    __syncthreads();
  }
  int s = s0 + ts;
  if (s < 129){
    float lmx = lmMax[b * 129 + s];
    #pragma unroll
    for (int j = 0; j < 8; ++j){
      int t = t0 + tt + 16 * j;
      normv[((size_t)(b * 129 + s)) * 512 + t] = __logf(acc[j]) + lmx + amMax[b * 512 + t];
    }
  }
}

// ---------- smoothed px/py, written DIAG-major ----------
__global__ __launch_bounds__(256) void k_pxpy(
    const float* __restrict__ am, const float* __restrict__ lm,
    const int* __restrict__ targets, const float* __restrict__ normv,
    const float* __restrict__ lmLse, float* __restrict__ pxd, float* __restrict__ pyd)
{
  int bs = blockIdx.x;           // b*129 + s
  int b = bs / 129, s = bs % 129;
  float lm0 = lm[(size_t)bs * 512];
  float lse = lmLse[bs];
  int sym = 0; float lms = 0.f;
  if (s < 128){ sym = targets[b * 128 + s]; lms = lm[(size_t)bs * 512 + sym]; }
  const float* nrm = normv + (size_t)bs * 512;
  float* pydb = pyd + (size_t)b * 640 * DPAD;
  float* pxdb = pxd + (size_t)b * 640 * DPAD;
  for (int t = threadIdx.x; t < 513; t += 256){
    if (t < 512){
      float n = nrm[t];
      float a0 = am[((size_t)(b * 512 + t)) * 512];
      pydb[(size_t)(s + t) * DPAD + s] = 0.75f * (a0 + lm0 - n) + 0.25f * (lm0 - lse);
      if (s < 128){
        float as = am[((size_t)(b * 512 + t)) * 512 + sym];
        pxdb[(size_t)(s + t) * DPAD + s] = 0.75f * (as + lms - n) + 0.25f * (lms - lse);
      }
    } else if (s < 128){
      pxdb[(size_t)(s + 512) * DPAD + s] = NEGV;
    }
  }
}

// ======================================================================
// Wave-systolic lattice DP over diagonal-major inputs.
// 3 waves x 43 rows per batch, lane = local row, ds_bpermute carries the
// vertical dependency, LDS 'bnd' carries cross-wave boundary rows with a
// 2-round skew. All global accesses are per-diagonal rows -> coalesced.
// ======================================================================

__global__ __launch_bounds__(192) void k_dp_fwd(
    const float* __restrict__ pxd, const float* __restrict__ pyd,
    float* __restrict__ pd, float* __restrict__ tot)
{
  int b = blockIdx.x;
  int tid = threadIdx.x;
  int w = tid >> 6, l = tid & 63;
  int s = 43 * w + l;
  bool act = (l < 43);
  bool haspx = act && (s >= 1);
  __shared__ float bnd[2][576];     // bnd[j][t] = p[43j+42][t]
  const float* pxdb = pxd + (size_t)b * 640 * DPAD;
  const float* pydb = pyd + (size_t)b * 640 * DPAD;
  float* pdb = pd + (size_t)b * 641 * DPAD;
  bool pstore = (pd != nullptr);
  float cur = 0.f;
  float pxb[2][8], pyb[2][8];
  int paddr = (l - 1) << 2;
  int sx = haspx ? (s - 1) : 0;

  auto LOADB = [&](int dl0, float* pxv, float* pyv){
    #pragma unroll
    for (int k = 0; k < 8; ++k){
      int dl = dl0 + k;
      int t = dl - l;
      int dc = 43 * w + dl - 1;
      dc = dc < 0 ? 0 : (dc > 639 ? 639 : dc);
      pxv[k] = (haspx && t >= 0 && t <= 512) ? pxdb[(size_t)dc * DPAD + sx] : NEGV;
      pyv[k] = (act && t >= 1 && t <= 512) ? pydb[(size_t)dc * DPAD + s] : NEGV;
    }
  };
  LOADB(0, pxb[0], pyb[0]);

  for (int r = 0; r < 13; ++r){
    if (r >= 2 * w && r < 2 * w + 9){
      int base = (r - 2 * w) * 64;
      #pragma unroll
      for (int blk = 0; blk < 8; ++blk){
        const int cb = blk & 1, nb = cb ^ 1;
        int dl0 = base + blk * 8;
        LOADB(dl0 + 8, pxb[nb], pyb[nb]);
        float bndv[8];
        {
          bool rd = (w > 0 && l == 0);
          #pragma unroll
          for (int k = 0; k < 8; ++k)
            bndv[k] = rd ? bnd[w - 1][dl0 + k] : NEGV;
        }
        #pragma unroll
        for (int k = 0; k < 8; ++k){
          int dl = dl0 + k;
          int t = dl - l;
          float upv = __int_as_float(
              __builtin_amdgcn_ds_bpermute(paddr, __float_as_int(cur)));
          if (l == 0) upv = bndv[k];
          float aa = upv + pxb[cb][k];
          float bb = cur + pyb[cb][k];
          float nv = lae(aa, bb);
          if (s == 0 && t == 0) nv = 0.f;
          if (act && t >= 0 && t <= 512){
            cur = nv;
            if (pstore) pdb[(size_t)(43 * w + dl) * DPAD + s] = cur;
            if (l == 42 && w < 2) bnd[w][t] = cur;
            if (s == 128 && t == 512) tot[b] = cur;
          }
        }
      }
    }
    __syncthreads();
  }
}

__global__ __launch_bounds__(192) void k_dp_bwd(
    const float* __restrict__ pxd, const float* __restrict__ pyd,
    const float* __restrict__ pd, const float* __restrict__ tot,
    float* __restrict__ gxd, float* __restrict__ gyd)
{
  int b = blockIdx.x;
  int tid = threadIdx.x;
  int w = tid >> 6, l = tid & 63;
  int s = 43 * w + l;
  bool act = (l < 43);
  bool haspx = act && (s < 128);
  __shared__ float bnd[2][576];     // bnd[j][t] = beta[43(j+1)][t]
  const float* pxdb = pxd + (size_t)b * 640 * DPAD;
  const float* pydb = pyd + (size_t)b * 640 * DPAD;
  const float* pdb = pd + (size_t)b * 641 * DPAD;
  float* gxdb = gxd + (size_t)b * 640 * DPAD;
  float* gydb = gyd + (size_t)b * 640 * DPAD;
  float tv = tot[b];
  float cur = 0.f;
  float pxb[2][8], pyb[2][8], pab[2][8];
  int paddr = (l + 1) << 2;
  int r0 = 2 * (2 - w);

  auto LOADB = [&](int dl0, float* pxv, float* pyv, float* pav){
    #pragma unroll
    for (int k = 0; k < 8; ++k){
      int dl = dl0 + k;
      int t = 554 - dl - l;
      int d = 554 + 43 * w - dl;
      int dc = d < 0 ? 0 : (d > 639 ? 639 : d);
      int dcp = d < 0 ? 0 : (d > 640 ? 640 : d);
      pxv[k] = (haspx && t >= 0 && t <= 512) ? pxdb[(size_t)dc * DPAD + s] : NEGV;
      pyv[k] = (act && t >= 0 && t <= 511) ? pydb[(size_t)dc * DPAD + s] : NEGV;
      pav[k] = (act && t >= 0 && t <= 512) ? pdb[(size_t)dcp * DPAD + s] : 0.f;
    }
  };
  LOADB(0, pxb[0], pyb[0], pab[0]);

  for (int r = 0; r < 13; ++r){
    if (r >= r0 && r < r0 + 9){
      int base = (r - r0) * 64;
      #pragma unroll
      for (int blk = 0; blk < 8; ++blk){
        const int cb = blk & 1, nb = cb ^ 1;
        int dl0 = base + blk * 8;
        LOADB(dl0 + 8, pxb[nb], pyb[nb], pab[nb]);
        float bndv[8];
        {
          bool rd = (w < 2 && l == 42);
          #pragma unroll
          for (int k = 0; k < 8; ++k){
            int ttv = 512 - dl0 - k;
            int idx = ttv < 0 ? 0 : ttv;
            bndv[k] = rd ? bnd[w][idx] : NEGV;
          }
        }
        #pragma unroll
        for (int k = 0; k < 8; ++k){
          int dl = dl0 + k;
          int t = 554 - dl - l;
          int d = s + t;
          float dnv = __int_as_float(
              __builtin_amdgcn_ds_bpermute(paddr, __float_as_int(cur)));
          if (l == 42) dnv = bndv[k];
          float aa = pxb[cb][k] + dnv;   // px[s][t] + beta[s+1][t]
          float bb = pyb[cb][k] + cur;   // py[s][t] + beta[s][t+1]
          float nv = lae(aa, bb);
          if (s == 128 && t == 512) nv = 0.f;
          if (act && t >= 0 && t <= 512){
            float pa = pab[cb][k];
            if (s < 128) gxdb[(size_t)d * DPAD + s] = __expf(pa + aa - tv);
            if (t < 512) gydb[(size_t)d * DPAD + s] = __expf(pa + bb - tv);
            cur = nv;
            if (l == 0 && w > 0) bnd[w - 1][t] = cur;
          }
        }
      }
    }
    __syncthreads();
  }
}

// ---------- sliding-window argmax over s for each (b,t), diag-major input ----------
__global__ __launch_bounds__(256) void k_window(
    const float* __restrict__ gxd, const float* __restrict__ gyd, int* __restrict__ sbr)
{
  __shared__ float tote[129][66];   // pad 66: conflict-free both phases
  int b = blockIdx.x >> 3;
  int t0 = (blockIdx.x & 7) << 6;
  const float* gx = gxd + (size_t)b * 640 * DPAD;
  const float* gy = gyd + (size_t)b * 640 * DPAD;
  int tid = threadIdx.x;
  int wv = tid >> 6, ln = tid & 63;
  for (int dd = wv; dd < 192; dd += 4){
    int d = t0 + dd;
    int slo = dd - 63 > 0 ? dd - 63 : 0;
    int shi = dd < 128 ? dd : 128;
    int s = slo + ln;
    if (s <= shi){
      float v = gy[(size_t)d * DPAD + s];
      if (s < 128) v += gx[(size_t)d * DPAD + s];
      tote[s][d - s - t0] = v;
    }
  }
  __syncthreads();
  if (tid < 64){
    int c = tid;
    float win = 0.f;
    for (int s = 0; s < 19; ++s) win += tote[s][c];
    float best = win; int arg = 0;
    for (int w2 = 1; w2 <= 110; ++w2){
      win += tote[w2 + 18][c] - tote[w2 - 1][c];
      if (win > best){ best = win; arg = w2; }   // strict > keeps first-index argmax
    }
    sbr[b * 512 + t0 + c] = arg;
  }
}

// ---------- monotone lower-bound adjust (single reverse pass per batch) ----------
__global__ void k_adjust(const int* __restrict__ sbr, int* __restrict__ sbeg){
  if (threadIdx.x != 0) return;
  int b = blockIdx.x;
  const int* in = sbr + b * 512;
  int* out = sbeg + b * 512;
  int sbm = 1 << 30, ym = 1 << 30;
  for (int t = 511; t >= 0; --t){
    sbm = min(sbm, in[t]);
    int y = 18 * t - sbm;
    ym = min(ym, y);
    int yc = ym > 0 ? ym : 0;
    out[t] = 18 * t - yc;
  }
}

// ---------- joiner: H=tanh(am+lm_pruned) bf16, logits=H@Wb+bias, fused logsumexp epilogue ----------
__global__ __launch_bounds__(256) void k_joiner(
    const float* __restrict__ am, const float* __restrict__ lm,
    const int* __restrict__ targets, const float* __restrict__ bias,
    const short* __restrict__ Wb, const int* __restrict__ sbeg,
    float* __restrict__ pxv, float* __restrict__ pyv)
{
  __shared__ short Hs[32][40];          // 32 rows x 32 k, row stride 40 (bank spread)
  __shared__ int rowSym[32];
  __shared__ int rowAm[32];
  __shared__ int rowLm[32];
  __shared__ float redM[32][4];
  __shared__ float redS[32][4];
  __shared__ float rowMax[32];
  __shared__ float rowNorm[32];

  int tid = threadIdx.x;
  int r0 = blockIdx.x * 32;
  if (tid < 32){
    int row = r0 + tid;
    int g = row / 19;
    int j = row - g * 19;
    int b = g >> 9;
    int t = g & 511;
    int start = sbeg[b * 512 + t];
    int sidx = start + j;               // <= 128 by construction
    rowSym[tid] = (sidx < 128) ? targets[b * 128 + sidx] : 0;
    rowAm[tid] = (b * 512 + t) * 512;
    rowLm[tid] = (b * 129 + sidx) * 512;
  }
  __syncthreads();

  int wv = tid >> 6, lane = tid & 63, q = lane >> 4, ln = lane & 15;
  int colBase = wv * 128 + ln;
  int hr = tid >> 3, kk = (tid & 7) * 4;

  floatx4 acc[2][8];
  #pragma unroll
  for (int mt = 0; mt < 2; ++mt)
    #pragma unroll
    for (int nt = 0; nt < 8; ++nt) acc[mt][nt] = (floatx4){0.f, 0.f, 0.f, 0.f};

  for (int k0 = 0; k0 < 512; k0 += 32){
    { // fused activation staging: 4 elems/thread
      const float* ap = am + (size_t)rowAm[hr] + k0 + kk;
      const float* lp = lm + (size_t)rowLm[hr] + k0 + kk;
      floatx4 a4 = *(const floatx4*)ap;
      floatx4 l4 = *(const floatx4*)lp;
      short4v h;
      h[0] = f2bf(fast_tanh(a4[0] + l4[0]));
      h[1] = f2bf(fast_tanh(a4[1] + l4[1]));
      h[2] = f2bf(fast_tanh(a4[2] + l4[2]));
      h[3] = f2bf(fast_tanh(a4[3] + l4[3]));
      *(short4v*)&Hs[hr][kk] = h;
    }
    __syncthreads();
    short8 afr0 = *(const short8*)&Hs[ln][q * 8];
    short8 afr1 = *(const short8*)&Hs[16 + ln][q * 8];
    #pragma unroll
    for (int nt = 0; nt < 8; ++nt){
      int col = colBase + nt * 16;
      short8 bfr = *(const short8*)(Wb + (size_t)col * 512 + k0 + q * 8);
      acc[0][nt] = __builtin_amdgcn_mfma_f32_16x16x32_bf16(afr0, bfr, acc[0][nt], 0, 0, 0);
      acc[1][nt] = __builtin_amdgcn_mfma_f32_16x16x32_bf16(afr1, bfr, acc[1][nt], 0, 0, 0);
    }
    __syncthreads();
  }

  // bias add
  #pragma unroll
  for (int nt = 0; nt < 8; ++nt){
    float bc = bias[colBase + nt * 16];
    #pragma unroll
    for (int mt = 0; mt < 2; ++mt)
      #pragma unroll
      for (int r = 0; r < 4; ++r) acc[mt][nt][r] += bc;
  }
  // per-row max
  #pragma unroll
  for (int mt = 0; mt < 2; ++mt)
    #pragma unroll
    for (int r = 0; r < 4; ++r){
      int row = mt * 16 + q * 4 + r;
      float m = acc[mt][0][r];
      #pragma unroll
      for (int nt = 1; nt < 8; ++nt) m = fmaxf(m, acc[mt][nt][r]);
      m = fmaxf(m, __shfl_xor(m, 1, 16));
      m = fmaxf(m, __shfl_xor(m, 2, 16));
      m = fmaxf(m, __shfl_xor(m, 4, 16));
      m = fmaxf(m, __shfl_xor(m, 8, 16));
      if (ln == 0) redM[row][wv] = m;
    }
  __syncthreads();
  if (tid < 32) rowMax[tid] = fmaxf(fmaxf(redM[tid][0], redM[tid][1]),
                                    fmaxf(redM[tid][2], redM[tid][3]));
  __syncthreads();
  // per-row sum of exp
  #pragma unroll
  for (int mt = 0; mt < 2; ++mt)
    #pragma unroll
    for (int r = 0; r < 4; ++r){
      int row = mt * 16 + q * 4 + r;
      float rm = rowMax[row];
      float sa = 0.f;
      #pragma unroll
      for (int nt = 0; nt < 8; ++nt) sa += __expf(acc[mt][nt][r] - rm);
      sa += __shfl_xor(sa, 1, 16);
      sa += __shfl_xor(sa, 2, 16);
      sa += __shfl_xor(sa, 4, 16);
      sa += __shfl_xor(sa, 8, 16);
      if (ln == 0) redS[row][wv] = sa;
    }
  __syncthreads();
  if (tid < 32) rowNorm[tid] = rowMax[tid] +
      __logf(redS[tid][0] + redS[tid][1] + redS[tid][2] + redS[tid][3]);
  __syncthreads();
  // extract logit[0] and logit[sym]
  #pragma unroll
  for (int mt = 0; mt < 2; ++mt)
    #pragma unroll
    for (int nt = 0; nt < 8; ++nt){
      int col = colBase + nt * 16;
      #pragma unroll
      for (int r = 0; r < 4; ++r){
        int row = mt * 16 + q * 4 + r;
        float v = acc[mt][nt][r] - rowNorm[row];
        int gr = r0 + row;
        if (col == 0) pyv[gr] = v;
        if (col == rowSym[row]) pxv[gr] = v;
      }
    }
}

// ---------- scatter band values into diag-major px2d / py2d ----------
__global__ __launch_bounds__(192) void k_band(
    const float* __restrict__ pxv, const float* __restrict__ pyv,
    const int* __restrict__ sbeg, float* __restrict__ px2d, float* __restrict__ py2d)
{
  int bd = blockIdx.x;         // b*640 + d
  int b = bd / 640, d = bd - b * 640;
  int s = threadIdx.x;
  int t = d - s;
  if (s > 128 || t < 0 || t > 512) return;
  size_t addr = (size_t)b * 640 * DPAD + (size_t)d * DPAD + s;
  if (s < 128){
    float v;
    if (t == 512) v = NEGV;
    else {
      int start = sbeg[b * 512 + t];
      int j = s - start;
      v = (j >= 0 && j < 19) ? pxv[((size_t)(b * 512 + t)) * 19 + j] : NEGV;
    }
    px2d[addr] = v;
  }
  if (t <= 511){
    int start = sbeg[b * 512 + t];
    int j = s - start;
    py2d[addr] = (j >= 0 && j < 19) ? pyv[((size_t)(b * 512 + t)) * 19 + j] : NEGV;
  }
}

// ---------- final scalar ----------
__global__ void k_final(const float* __restrict__ tots, const float* __restrict__ totp,
                        float* __restrict__ out){
  if (blockIdx.x == 0 && threadIdx.x == 0){
    float a = 0.f, c = 0.f;
    for (int i = 0; i < 8; ++i){ a += tots[i]; c += totp[i]; }
    out[0] = -0.1f * (a * 0.125f) - (c * 0.125f);
  }
}

extern "C" void kernel_launch(void* const* d_in, const int* in_sizes, int n_in,
                              void* d_out, int out_size, void* d_ws, size_t ws_size,
                              hipStream_t stream){
  (void)in_sizes; (void)n_in; (void)out_size; (void)ws_size;
  const float* am      = (const float*)d_in[0];
  const float* lm      = (const float*)d_in[1];
  const int*   targets = (const int*)d_in[2];
  const float* W       = (const float*)d_in[4];
  const float* bias    = (const float*)d_in[5];
  float* out = (float*)d_out;

  char* base = (char*)d_ws;
  size_t off = 0;
  auto alloc = [&](size_t bytes) -> char* {
    char* r = base + off;
    off += (bytes + 255) & ~(size_t)255;
    return r;
  };
  const size_t DROWS = 640ull * DPAD;   // per-batch diag elems (px/py/gx/gy)
  float* amMax = (float*)alloc(8ull * 512 * 4);
  float* lmMax = (float*)alloc(8ull * 129 * 4);
  float* lmLse = (float*)alloc(8ull * 129 * 4);
  float* normv = (float*)alloc(8ull * 129 * 512 * 4);
  float* pxd   = (float*)alloc(8ull * DROWS * 4);
  float* pyd   = (float*)alloc(8ull * DROWS * 4);
  float* pd    = (float*)alloc(8ull * 641 * DPAD * 4);
  float* gxd   = (float*)alloc(8ull * DROWS * 4);
  float* gyd   = (float*)alloc(8ull * DROWS * 4);
  float* tots  = (float*)alloc(8 * 4);
  float* totp  = (float*)alloc(8 * 4);
  int*   sbr   = (int*)alloc(8ull * 512 * 4);
  int*   sbeg  = (int*)alloc(8ull * 512 * 4);
  float* pxv   = (float*)alloc(8ull * 512 * 19 * 4);
  float* pyv   = (float*)alloc(8ull * 512 * 19 * 4);
  short* Wb    = (short*)alloc(512ull * 512 * 2);
  float* px2d  = pxd;   // alias: pxd/pyd dead after k_dp_bwd
  float* py2d  = pyd;

  k_row_stats<<<dim3(4096), dim3(256), 0, stream>>>(am, amMax, (float*)nullptr);
  k_row_stats<<<dim3(1032), dim3(256), 0, stream>>>(lm, lmMax, lmLse);
  k_wb<<<dim3(1024), dim3(256), 0, stream>>>(W, Wb);
  k_norm<<<dim3(4, 9, 8), dim3(256), 0, stream>>>(am, lm, lmMax, amMax, normv);
  k_pxpy<<<dim3(1032), dim3(256), 0, stream>>>(am, lm, targets, normv, lmLse, pxd, pyd);
  k_dp_fwd<<<dim3(8), dim3(192), 0, stream>>>(pxd, pyd, pd, tots);
  k_dp_bwd<<<dim3(8), dim3(192), 0, stream>>>(pxd, pyd, pd, tots, gxd, gyd);
  k_window<<<dim3(64), dim3(256), 0, stream>>>(gxd, gyd, sbr);
  k_adjust<<<dim3(8), dim3(64), 0, stream>>>(sbr, sbeg);
  k_joiner<<<dim3(2432), dim3(256), 0, stream>>>(am, lm, targets, bias, Wb, sbeg, pxv, pyv);
  k_band<<<dim3(5120), dim3(192), 0, stream>>>(pxv, pyv, sbeg, px2d, py2d);
  k_dp_fwd<<<dim3(8), dim3(192), 0, stream>>>(px2d, py2d, (float*)nullptr, totp);
  k_final<<<dim3(1), dim3(64), 0, stream>>>(tots, totp, out);
}